// Round 11
// baseline (690.829 us; speedup 1.0000x reference)
//
#include <hip/hip_runtime.h>
#include <hip/hip_bf16.h>

#define B_   8
#define S_   4096
#define D_   1024
#define M_   (B_ * S_)   // 32768 rows
#define N_   (2 * D_)    // 2048 cols (hidden | gate)
#define K_   D_          // 1024
#define CCH  128         // scan chunks
#define LCH  32          // chunk length (CCH*LCH == S_)

#define BK   32
#define NT   (K_ / BK)   // 32 k-tiles

typedef __attribute__((ext_vector_type(8))) short bf16x8;
typedef __attribute__((ext_vector_type(4))) float f32x4;

__device__ __forceinline__ unsigned short f2bf(float f) {
  union { float f; unsigned u; } v; v.f = f;
  unsigned u = v.u;
  u = u + 0x7fffu + ((u >> 16) & 1u);   // RNE
  return (unsigned short)(u >> 16);
}
__device__ __forceinline__ float bf2f(unsigned short h) {
  union { unsigned u; float f; } v; v.u = ((unsigned)h) << 16;
  return v.f;
}
__device__ __forceinline__ float sigmoidf_(float x) {
  return 1.0f / (1.0f + __expf(-x));
}
__device__ __forceinline__ unsigned short bfu(float f) {
  __hip_bfloat16 h = __float2bfloat16(f);            // RNE
  return *reinterpret_cast<unsigned short*>(&h);
}
__device__ __forceinline__ bf16x8 pk8(float4 a, float4 b) {
  union { bf16x8 v; unsigned short u[8]; } r;
  r.u[0] = bfu(a.x); r.u[1] = bfu(a.y); r.u[2] = bfu(a.z); r.u[3] = bfu(a.w);
  r.u[4] = bfu(b.x); r.u[5] = bfu(b.y); r.u[6] = bfu(b.z); r.u[7] = bfu(b.w);
  return r.v;
}

#define GLL(src, dst) __builtin_amdgcn_global_load_lds(                     \
      (const __attribute__((address_space(1))) void*)(src),                 \
      (__attribute__((address_space(3))) void*)(dst), 16, 0, 0)

// ---------- fp32 -> bf16 convert (W only; x is converted inside k_gemm) ----
__global__ __launch_bounds__(256) void k_cvtw(const float* __restrict__ W,
                                              unsigned short* __restrict__ wb) {
  const int i = blockIdx.x * 256 + threadIdx.x;      // 2048 blocks -> 524288
  float4 v = reinterpret_cast<const float4*>(W)[i];
  ushort4 o;
  o.x = f2bf(v.x); o.y = f2bf(v.y); o.z = f2bf(v.z); o.w = f2bf(v.w);
  reinterpret_cast<ushort4*>(wb)[i] = o;
}

// ---------- bf16 GEMM (f32 x read + in-kernel cvt) + fused chunk-scan ------
// R11 changes vs R10:
//  (1) A staged from f32 x directly: per tile issue 4 float4 loads (t+2) +
//      1 B-GLL(t+2); at tile end vmcnt(5) drains only t-1's 5 ops, then cvt
//      16 f32->bf16 + 2 ds_write_b128 into slot(t+1), lgkm0+barrier. Two
//      named reg sets (E/O) alternate by parity. Kills the 204MB x-cvt pass.
//  (2) epilogue hi==3 lanes store chunk-total (A,B) to dense f32 Atot/Btot
//      planes -> scan2 reverts to the proven dense f32x4 form.
// Unchanged: pair-row swizzle LDS layout (0 conflicts), frag reads, MFMA
// cluster, setprio, 2 WG/CU, XCD swizzle, plain epilogue stores.
__global__ __launch_bounds__(512, 4) void k_gemm(const float* __restrict__ xf,
                                                 const unsigned short* __restrict__ wb,
                                                 unsigned short* __restrict__ HLp,
                                                 unsigned short* __restrict__ APp,
                                                 float* __restrict__ Atot,
                                                 float* __restrict__ Btot) {
  // 3 slots x (A 256x32 16KB | B 128x32 8KB) = 72 KiB
  __shared__ unsigned short lds[36864];
  const int tid = threadIdx.x;
  int wg = blockIdx.x;
  wg = (wg & 7) * 256 + (wg >> 3);     // XCD swizzle; 2048 % 8 == 0 -> bijective
  const int bm = wg >> 4;              // 0..127  (256-row panels)
  const int bn = wg & 15;              // 0..15   (64-d-col panels, paired)
  const int lane = tid & 63;
  const int wid = tid >> 6;            // 0..7
  const int wrr = wid >> 1;            // 0..3 (64-row band)
  const int wcc = wid & 1;             // 0..1 (32-d-col band)
  const int fr = lane & 15;
  const int hi = lane >> 4;            // 0..3

  // staging: srow = tid>>2 (0..127), slot i = tid&3; pair-row swizzle:
  // fetch logical blk j = i ^ ((srow>>1)&3). A source is f32 (32B blocks).
  const int srow = tid >> 2;
  const int sblk = (tid & 3) ^ ((srow >> 1) & 3);
  const char* aSf = (const char*)xf + (size_t)(bm * 256 + srow) * 4096 + sblk * 32;
  const char* bS = (const char*)wb +
      (size_t)(bn * 64 + srow + ((srow >= 64) ? 960 : 0)) * 2048 + sblk * 16;
  char* const ldsc = (char*)lds + (size_t)tid * 16;   // per-thread stage dest
  const char* const ldsr = (const char*)lds;          // read base

  const int sA = ((hi ^ ((fr >> 1) & 3)) * 16);
  const int arow  = (wrr * 64 + fr) * 64;             // A byte row base (m=0)
  const int browH = 16384 + (wcc * 32 + fr) * 64;     // B hidden rows
  const int browG = browH + 4096;                     // B gate rows (+64 rows)

  f32x4 accH[4][2] = {};
  f32x4 accG[4][2] = {};
  bf16x8 av[4], bvH[2], bvG[2];
  float4 e0, e1, e2, e3, o0, o1, o2, o3;

  int sl = 0;        // slot(t)   read base
  int sn1 = 24576;   // slot(t+1) A ds_write base
  int sn2 = 49152;   // slot(t+2) B GLL base

  // prologue: issue group(0) then group(1); drain group(0); write A(0)
  GLL(bS, ldsc + 16384);                       // B(0) -> slot0
  e0 = *(const float4*)(aSf);
  e1 = *(const float4*)(aSf + 16);
  e2 = *(const float4*)(aSf + 524288);         // +128 rows
  e3 = *(const float4*)(aSf + 524288 + 16);
  asm volatile("" ::: "memory");               // pin group order
  GLL(bS + 64, ldsc + 40960);                  // B(1) -> slot1
  o0 = *(const float4*)(aSf + 128);
  o1 = *(const float4*)(aSf + 128 + 16);
  o2 = *(const float4*)(aSf + 524288 + 128);
  o3 = *(const float4*)(aSf + 524288 + 128 + 16);
  asm volatile("s_waitcnt vmcnt(5)" ::: "memory");   // A(0) regs + B(0) LDS done
  *(bf16x8*)(ldsc)        = pk8(e0, e1);
  *(bf16x8*)(ldsc + 8192) = pk8(e2, e3);
  asm volatile("s_waitcnt lgkmcnt(0)\n\ts_barrier" ::: "memory");

#define TILE(T, I0, I1, I2, I3, W0, W1, W2, W3)                               \
  {                                                                           \
    const int t_ = (T);                                                       \
    if (t_ < NT - 2) {                                                        \
      const size_t kb = (size_t)(t_ + 2) * 128;                               \
      GLL(bS + (size_t)(t_ + 2) * 64, ldsc + sn2 + 16384);                    \
      I0 = *(const float4*)(aSf + kb);                                        \
      I1 = *(const float4*)(aSf + kb + 16);                                   \
      I2 = *(const float4*)(aSf + kb + 524288);                               \
      I3 = *(const float4*)(aSf + kb + 524288 + 16);                          \
    }                                                                         \
    const char* Ab = ldsr + sl;                                               \
    _Pragma("unroll") for (int m = 0; m < 4; ++m)                             \
      av[m] = *(const bf16x8*)(Ab + arow + m * 1024 + sA);                    \
    _Pragma("unroll") for (int n = 0; n < 2; ++n) {                           \
      bvH[n] = *(const bf16x8*)(Ab + browH + n * 1024 + sA);                  \
      bvG[n] = *(const bf16x8*)(Ab + browG + n * 1024 + sA);                  \
    }                                                                         \
    __builtin_amdgcn_s_setprio(1);                                            \
    _Pragma("unroll") for (int m = 0; m < 4; ++m)                             \
      _Pragma("unroll") for (int n = 0; n < 2; ++n) {                         \
        accH[m][n] = __builtin_amdgcn_mfma_f32_16x16x32_bf16(av[m], bvH[n],   \
                                                             accH[m][n], 0, 0, 0); \
        accG[m][n] = __builtin_amdgcn_mfma_f32_16x16x32_bf16(av[m], bvG[n],   \
                                                             accG[m][n], 0, 0, 0); \
      }                                                                       \
    __builtin_amdgcn_s_setprio(0);                                            \
    if (t_ < NT - 2)       asm volatile("s_waitcnt vmcnt(5)" ::: "memory");   \
    else if (t_ == NT - 2) asm volatile("s_waitcnt vmcnt(0)" ::: "memory");   \
    if (t_ < NT - 1) {                                                        \
      *(bf16x8*)(ldsc + sn1)        = pk8(W0, W1);                            \
      *(bf16x8*)(ldsc + sn1 + 8192) = pk8(W2, W3);                            \
      asm volatile("s_waitcnt lgkmcnt(0)\n\ts_barrier" ::: "memory");         \
    }                                                                         \
    sl += 24576;  if (sl == 73728) sl = 0;                                    \
    sn1 += 24576; if (sn1 == 73728) sn1 = 0;                                  \
    sn2 += 24576; if (sn2 == 73728) sn2 = 0;                                  \
  }

  for (int tt = 0; tt < NT / 2; ++tt) {
    TILE(2 * tt,     e0, e1, e2, e3, o0, o1, o2, o3);
    TILE(2 * tt + 1, o0, o1, o2, o3, e0, e1, e2, e3);
  }
#undef TILE

  // ---- fused epilogue: per-chunk (32-step) scan; writes hl/ap bf16 planes
  // + dense f32 chunk totals (hi==3). C/D layout col=lane&15, row=(lane>>4)*4+reg.
  const int dcol0 = bn * 64 + wcc * 32 + fr;
  const size_t rowg0 = (size_t)(bm * 256 + wrr * 64);
#pragma unroll
  for (int kap = 0; kap < 2; ++kap) {
#pragma unroll
    for (int n = 0; n < 2; ++n) {
      float a_[2][4], b_[2][4];
#pragma unroll
      for (int mm = 0; mm < 2; ++mm)
#pragma unroll
        for (int i = 0; i < 4; ++i) {
          float zg = sigmoidf_(accG[kap * 2 + mm][n][i]);
          float hv = accH[kap * 2 + mm][n][i];
          float gg = (hv >= 0.f) ? (hv + 0.5f) : sigmoidf_(hv);
          a_[mm][i] = 1.f - zg;
          b_[mm][i] = zg * gg;
        }
      // per-lane 4-step segment transforms T(h)=A*h+B
      float A1 = a_[0][0] * a_[0][1] * a_[0][2] * a_[0][3];
      float B1 = ((b_[0][0] * a_[0][1] + b_[0][1]) * a_[0][2] + b_[0][2]) * a_[0][3] + b_[0][3];
      float A2 = a_[1][0] * a_[1][1] * a_[1][2] * a_[1][3];
      float B2 = ((b_[1][0] * a_[1][1] + b_[1][1]) * a_[1][2] + b_[1][2]) * a_[1][3] + b_[1][3];
      // Hillis-Steele inclusive compose across hi groups
      float Ai = A1, Bi = B1;
      { float Ao = __shfl(Ai, (lane - 16) & 63), Bo = __shfl(Bi, (lane - 16) & 63);
        if (hi >= 1) { Bi += Ai * Bo; Ai *= Ao; } }
      { float Ao = __shfl(Ai, (lane - 32) & 63), Bo = __shfl(Bi, (lane - 32) & 63);
        if (hi >= 2) { Bi += Ai * Bo; Ai *= Ao; } }
      float Ae1 = __shfl(Ai, (lane - 16) & 63), Be1 = __shfl(Bi, (lane - 16) & 63);
      if (hi == 0) { Ae1 = 1.f; Be1 = 0.f; }
      float At = __shfl(Ai, fr + 48), Bt = __shfl(Bi, fr + 48);  // total s0..15
      float Ai2 = A2, Bi2 = B2;
      { float Ao = __shfl(Ai2, (lane - 16) & 63), Bo = __shfl(Bi2, (lane - 16) & 63);
        if (hi >= 1) { Bi2 += Ai2 * Bo; Ai2 *= Ao; } }
      { float Ao = __shfl(Ai2, (lane - 32) & 63), Bo = __shfl(Bi2, (lane - 32) & 63);
        if (hi >= 2) { Bi2 += Ai2 * Bo; Ai2 *= Ao; } }
      float Ae2 = __shfl(Ai2, (lane - 16) & 63), Be2 = __shfl(Bi2, (lane - 16) & 63);
      if (hi == 0) { Ae2 = 1.f; Be2 = 0.f; }
      const float Ax2 = Ae2 * At;            // exclusive prefix for 2nd segment
      const float Bx2 = Be2 + Ae2 * Bt;
      // replay + store hl/ap (plain stores; L2 merges)
      const int d = dcol0 + n * 16;
      size_t rr = (rowg0 + kap * 32 + hi * 4) * 1024 + d;
      float ap = Ae1, hl = Be1;
#pragma unroll
      for (int i = 0; i < 4; ++i) {
        hl = a_[0][i] * hl + b_[0][i]; ap *= a_[0][i];
        HLp[rr] = f2bf(hl);
        APp[rr] = f2bf(ap);
        rr += 1024;
      }
      rr = (rowg0 + kap * 32 + 16 + hi * 4) * 1024 + d;
      ap = Ax2; hl = Bx2;
#pragma unroll
      for (int i = 0; i < 4; ++i) {
        hl = a_[1][i] * hl + b_[1][i]; ap *= a_[1][i];
        HLp[rr] = f2bf(hl);
        APp[rr] = f2bf(ap);
        rr += 1024;
      }
      if (hi == 3) {  // chunk total (f32) -> dense planes
        const int rg = (int)rowg0 + kap * 32;
        const size_t ci = (size_t)((rg >> 5) & 127) * 8192 + (size_t)(rg >> 12) * 1024 + d;
        Atot[ci] = ap;
        Btot[ci] = hl;
      }
    }
  }
}

// ---------- scan phase 2: carry chain over dense f32 chunk totals ----------
__global__ __launch_bounds__(256) void k_scan2(const float* __restrict__ Atot,
                                               const float* __restrict__ Btot,
                                               float* __restrict__ Cin) {
  const int gid = blockIdx.x * 256 + threadIdx.x;   // 0..2047 (float4 over 8192)
  float4 carry = {0.f, 0.f, 0.f, 0.f};
  for (int c = 0; c < CCH; ++c) {
    reinterpret_cast<float4*>(Cin)[(size_t)c * 2048 + gid] = carry;
    float4 a  = reinterpret_cast<const float4*>(Atot)[(size_t)c * 2048 + gid];
    float4 bt = reinterpret_cast<const float4*>(Btot)[(size_t)c * 2048 + gid];
    carry.x = fmaf(a.x, carry.x, bt.x);
    carry.y = fmaf(a.y, carry.y, bt.y);
    carry.z = fmaf(a.z, carry.z, bt.z);
    carry.w = fmaf(a.w, carry.w, bt.w);
  }
}

// ---------- scan phase 3: out = hl + ap * carry ----------------------------
__global__ __launch_bounds__(256) void k_scan3(const unsigned short* __restrict__ HL,
                                               const unsigned short* __restrict__ AP,
                                               const float* __restrict__ Cin,
                                               float* __restrict__ out) {
  const int gid = blockIdx.x * 256 + threadIdx.x;
  const int c = blockIdx.y;
  const int b = gid >> 8;
  const int d0 = (gid & 255) << 2;
  float4 carry = reinterpret_cast<const float4*>(Cin)[(size_t)c * 2048 + gid];
  size_t off = ((size_t)b * S_ + (size_t)c * LCH) * 1024 + d0;
#pragma unroll 8
  for (int s = 0; s < LCH; ++s) {
    ushort4 hu = *reinterpret_cast<const ushort4*>(HL + off);
    ushort4 au = *reinterpret_cast<const ushort4*>(AP + off);
    float4 o;
    o.x = fmaf(bf2f(au.x), carry.x, bf2f(hu.x));
    o.y = fmaf(bf2f(au.y), carry.y, bf2f(hu.y));
    o.z = fmaf(bf2f(au.z), carry.z, bf2f(hu.z));
    o.w = fmaf(bf2f(au.w), carry.w, bf2f(hu.w));
    *reinterpret_cast<float4*>(out + off) = o;
    off += 1024;
  }
}

extern "C" void kernel_launch(void* const* d_in, const int* in_sizes, int n_in,
                              void* d_out, int out_size, void* d_ws, size_t ws_size,
                              hipStream_t stream) {
  const float* x = (const float*)d_in[0];   // [8,4096,1024] f32
  const float* W = (const float*)d_in[1];   // [2048,1024]  f32
  float* out = (float*)d_out;               // [8,4096,1024] f32

  unsigned char* w = (unsigned char*)d_ws;
  // layout: wb(4MB) | HL(64MB) | AP(64MB) | Atot(4MB) | Btot(4MB) | Cin(4MB)
  unsigned short* wb   = (unsigned short*)(w);
  unsigned short* HLp  = (unsigned short*)(w + 4194304);
  unsigned short* APp  = (unsigned short*)(w + 71303168);
  float* Atot = (float*)(w + 138412032);
  float* Btot = (float*)(w + 142606336);
  float* Cin  = (float*)(w + 146800640);

  k_cvtw<<<2048, 256, 0, stream>>>(W, wb);
  k_gemm<<<(M_ / 256) * 16, 512, 0, stream>>>(x, wb, HLp, APp, Atot, Btot);
  k_scan2<<<8, 256, 0, stream>>>(Atot, Btot, Cin);
  k_scan3<<<dim3(8, CCH), 256, 0, stream>>>(HLp, APp, Cin, out);
}